// Round 1
// baseline (3021.071 us; speedup 1.0000x reference)
//
#include <hip/hip_runtime.h>
#include <math.h>

#define NA 100000
#define NP 150000
#define EMB 64
#define NE 3200000
#define BATCH 65536
#define EPS 1e-8f

// ---------------- kernels ----------------

__global__ void deg_kernel(const int* __restrict__ ea, const int* __restrict__ ep,
                           float* __restrict__ deg_a, float* __restrict__ deg_p, int ne) {
    int e = blockIdx.x * blockDim.x + threadIdx.x;
    if (e < ne) {
        atomicAdd(&deg_a[ea[e]], 1.0f);
        atomicAdd(&deg_p[ep[e]], 1.0f);
    }
}

__global__ void norm_kernel(const int* __restrict__ ea, const int* __restrict__ ep,
                            const float* __restrict__ deg_a, const float* __restrict__ deg_p,
                            float* __restrict__ norm, int ne) {
    int e = blockIdx.x * blockDim.x + threadIdx.x;
    if (e < ne) {
        float da = deg_a[ea[e]] + EPS;
        float dp = deg_p[ep[e]] + EPS;
        norm[e] = rsqrtf(da * dp);
    }
}

// layer-1 init: out = u_sw * emb   (u_sw = 1 - deg/(deg+eps))
__global__ void init_l1(const float* __restrict__ emb, const float* __restrict__ deg,
                        float* __restrict__ out, int n_elems) {
    int i = blockIdx.x * blockDim.x + threadIdx.x;
    if (i < n_elems) {
        float d = deg[i >> 6];
        float sw = 1.0f - d / (d + EPS);
        out[i] = sw * emb[i];
    }
}

// layer-2 init: out = emb + (1 + u_sw) * l1
// (final = emb + l1 + l2 where l2 = u_sw*l1 + scatter; scatter added later)
__global__ void init_l2(const float* __restrict__ emb, const float* __restrict__ l1,
                        const float* __restrict__ deg, float* __restrict__ out, int n_elems) {
    int i = blockIdx.x * blockDim.x + threadIdx.x;
    if (i < n_elems) {
        float d = deg[i >> 6];
        float sw = 1.0f - d / (d + EPS);
        out[i] = emb[i] + (1.0f + sw) * l1[i];
    }
}

// one wave (64 lanes) per edge; lane = embedding dim
__global__ void scatter_kernel(const int* __restrict__ ea, const int* __restrict__ ep,
                               const float* __restrict__ norm,
                               const float* __restrict__ src_a, const float* __restrict__ src_p,
                               float* __restrict__ dst_a, float* __restrict__ dst_p, int ne) {
    int t = blockIdx.x * blockDim.x + threadIdx.x;
    int e = t >> 6;
    int d = t & 63;
    if (e < ne) {
        int a = ea[e];
        int p = ep[e];
        float nm = norm[e];
        // author -> paper
        atomicAdd(&dst_p[p * EMB + d], src_a[a * EMB + d] * nm);
        // paper -> author
        atomicAdd(&dst_a[a * EMB + d], src_p[p * EMB + d] * nm);
    }
}

// one wave per batch element: gather rows, write them out, dot-reduce, sigmoid
__global__ void gather_kernel(const float* __restrict__ fa, const float* __restrict__ fp,
                              const int* __restrict__ authors, const int* __restrict__ papers,
                              float* __restrict__ out, int batch) {
    int t = blockIdx.x * blockDim.x + threadIdx.x;
    int b = t >> 6;
    int d = t & 63;
    if (b >= batch) return;
    float la = fa[authors[b] * EMB + d];
    float lp = fp[papers[b] * EMB + d];
    out[batch + b * EMB + d] = la;                 // latest_author
    out[batch + batch * EMB + b * EMB + d] = lp;   // latest_paper
    float prod = la * lp;
    #pragma unroll
    for (int off = 32; off > 0; off >>= 1)
        prod += __shfl_down(prod, off, 64);
    if (d == 0)
        out[b] = 1.0f / (1.0f + expf(-prod));      // predict
}

// ---------------- launch ----------------

extern "C" void kernel_launch(void* const* d_in, const int* in_sizes, int n_in,
                              void* d_out, int out_size, void* d_ws, size_t ws_size,
                              hipStream_t stream) {
    const float* author_emb = (const float*)d_in[0];   // [NA, 64]
    const float* paper_emb  = (const float*)d_in[1];   // [NP, 64]
    const int*   authors    = (const int*)d_in[2];     // [BATCH]
    const int*   papers     = (const int*)d_in[3];     // [BATCH]
    const int*   edge_a     = (const int*)d_in[4];     // [NE]
    const int*   edge_p     = (const int*)d_in[5];     // [NE]
    float* out = (float*)d_out;

    // workspace layout (256B aligned)
    char* ws = (char*)d_ws;
    size_t off = 0;
    auto alloc = [&](size_t bytes) {
        void* p = ws + off;
        off += (bytes + 255) & ~(size_t)255;
        return p;
    };
    float* deg_a = (float*)alloc(NA * sizeof(float));
    float* deg_p = (float*)alloc(NP * sizeof(float));
    float* norm  = (float*)alloc((size_t)NE * sizeof(float));
    float* a1    = (float*)alloc((size_t)NA * EMB * sizeof(float));
    float* p1    = (float*)alloc((size_t)NP * EMB * sizeof(float));
    float* fa    = (float*)alloc((size_t)NA * EMB * sizeof(float));
    float* fp    = (float*)alloc((size_t)NP * EMB * sizeof(float));
    (void)ws_size;

    // 1. degrees (zero first; ws is poisoned)
    hipMemsetAsync(deg_a, 0, NA * sizeof(float), stream);
    hipMemsetAsync(deg_p, 0, NP * sizeof(float), stream);
    deg_kernel<<<(NE + 255) / 256, 256, 0, stream>>>(edge_a, edge_p, deg_a, deg_p, NE);

    // 2. per-edge norm
    norm_kernel<<<(NE + 255) / 256, 256, 0, stream>>>(edge_a, edge_p, deg_a, deg_p, norm, NE);

    // 3. layer 1: init self term, scatter messages
    init_l1<<<(NA * EMB + 255) / 256, 256, 0, stream>>>(author_emb, deg_a, a1, NA * EMB);
    init_l1<<<(NP * EMB + 255) / 256, 256, 0, stream>>>(paper_emb, deg_p, p1, NP * EMB);
    {
        long long total = (long long)NE * 64;
        scatter_kernel<<<(unsigned)((total + 255) / 256), 256, 0, stream>>>(
            edge_a, edge_p, norm, author_emb, paper_emb, a1, p1, NE);
    }

    // 4. layer 2 folded into final sum: f = emb + (1+sw)*l1 + scatter(l1)
    init_l2<<<(NA * EMB + 255) / 256, 256, 0, stream>>>(author_emb, a1, deg_a, fa, NA * EMB);
    init_l2<<<(NP * EMB + 255) / 256, 256, 0, stream>>>(paper_emb, p1, deg_p, fp, NP * EMB);
    {
        long long total = (long long)NE * 64;
        scatter_kernel<<<(unsigned)((total + 255) / 256), 256, 0, stream>>>(
            edge_a, edge_p, norm, a1, p1, fa, fp, NE);
    }

    // 5. batch gather + predict
    {
        long long total = (long long)BATCH * 64;
        gather_kernel<<<(unsigned)((total + 255) / 256), 256, 0, stream>>>(
            fa, fp, authors, papers, out, BATCH);
    }
}

// Round 2
// 1611.764 us; speedup vs baseline: 1.8744x; 1.8744x over previous
//
#include <hip/hip_runtime.h>
#include <math.h>

#define NA 100000
#define NP 150000
#define EMB 64
#define NE 3200000
#define BATCH 65536
#define EPS 1e-8f

// ---------------- CSR build ----------------

__global__ void count_kernel(const int* __restrict__ ea, const int* __restrict__ ep,
                             int* __restrict__ cnt_a, int* __restrict__ cnt_p) {
    int e = blockIdx.x * blockDim.x + threadIdx.x;
    if (e < NE) {
        atomicAdd(&cnt_a[ea[e]], 1);
        atomicAdd(&cnt_p[ep[e]], 1);
    }
}

// block-level exclusive scan (256/block), partial offsets + block sums
__global__ void scan_part(const int* __restrict__ cnt, int* __restrict__ off,
                          int* __restrict__ bsum, int n) {
    __shared__ int s[256];
    int t = threadIdx.x;
    int i = blockIdx.x * 256 + t;
    int x = (i < n) ? cnt[i] : 0;
    s[t] = x;
    __syncthreads();
    for (int o = 1; o < 256; o <<= 1) {
        int v = (t >= o) ? s[t - o] : 0;
        __syncthreads();
        s[t] += v;
        __syncthreads();
    }
    if (i < n) off[i] = s[t] - x;          // exclusive within block
    if (t == 255) bsum[blockIdx.x] = s[255];
}

// single-block exclusive scan of block sums (nb <= 1024)
__global__ void scan_top(int* __restrict__ bsum, int nb) {
    __shared__ int s[1024];
    int t = threadIdx.x;
    int x = (t < nb) ? bsum[t] : 0;
    s[t] = x;
    __syncthreads();
    for (int o = 1; o < 1024; o <<= 1) {
        int v = (t >= o) ? s[t - o] : 0;
        __syncthreads();
        s[t] += v;
        __syncthreads();
    }
    if (t < nb) bsum[t] = s[t] - x;
}

__global__ void scan_add(int* __restrict__ off, const int* __restrict__ bsum, int n, int total) {
    int i = blockIdx.x * 256 + threadIdx.x;
    if (i < n) off[i] += bsum[blockIdx.x];
    if (i == 0) off[n] = total;
}

// per-node rsqrt(deg+eps) factors + cursor init (cursor = copy of offsets)
__global__ void node_prep(const int* __restrict__ off_a, const int* __restrict__ off_p,
                          float* __restrict__ rs_a, float* __restrict__ rs_p,
                          int* __restrict__ cur_a, int* __restrict__ cur_p) {
    int i = blockIdx.x * blockDim.x + threadIdx.x;
    if (i < NA) {
        int d = off_a[i + 1] - off_a[i];
        rs_a[i] = rsqrtf((float)d + EPS);
        cur_a[i] = off_a[i];
    }
    if (i < NP) {
        int d = off_p[i + 1] - off_p[i];
        rs_p[i] = rsqrtf((float)d + EPS);
        cur_p[i] = off_p[i];
    }
}

__global__ void fill_kernel(const int* __restrict__ ea, const int* __restrict__ ep,
                            int* __restrict__ cur_a, int* __restrict__ cur_p,
                            int* __restrict__ csr_a, int* __restrict__ csr_p) {
    int e = blockIdx.x * blockDim.x + threadIdx.x;
    if (e < NE) {
        int a = ea[e], p = ep[e];
        int sa = atomicAdd(&cur_a[a], 1);
        csr_a[sa] = p;                      // author's incident papers
        int sp = atomicAdd(&cur_p[p], 1);
        csr_p[sp] = a;                      // paper's incident authors
    }
}

// ---------------- pull-based conv ----------------
// one wave (64 lanes = 64 dims) per destination node, no atomics.
// out[n] = coef_emb*emb[n] + coef_prev*prev[n] + rs_dst[n] * sum_e rs_src[src_e]*src[src_e]
// LAYER 1: coef_emb = sw(deg), coef_prev = 0, src = emb
// LAYER 2: coef_emb = 1, coef_prev = 1+sw(deg), src = prev
// WHICH: 0 = papers+authors fused, 1 = papers only, 2 = authors only
template <int LAYER, int WHICH>
__global__ void pull_kernel(const int* __restrict__ off_a, const int* __restrict__ off_p,
                            const int* __restrict__ csr_a, const int* __restrict__ csr_p,
                            const float* __restrict__ rs_a, const float* __restrict__ rs_p,
                            const float* __restrict__ a_emb, const float* __restrict__ p_emb,
                            const float* __restrict__ a_prev, const float* __restrict__ p_prev,
                            float* __restrict__ a_out, float* __restrict__ p_out) {
    int wave = (int)(((size_t)blockIdx.x * blockDim.x + threadIdx.x) >> 6);
    int lane = threadIdx.x & 63;

    int n;
    const int *off, *csr;
    const float *rsd, *rss, *emb, *prev, *src;
    float* o;
    bool is_paper;
    if (WHICH == 0) {
        if (wave < NP) { is_paper = true; n = wave; }
        else if (wave < NP + NA) { is_paper = false; n = wave - NP; }
        else return;
    } else if (WHICH == 1) {
        if (wave >= NP) return;
        is_paper = true; n = wave;
    } else {
        if (wave >= NA) return;
        is_paper = false; n = wave;
    }
    if (is_paper) {
        off = off_p; csr = csr_p; rsd = rs_p; rss = rs_a;
        emb = p_emb; prev = p_prev; src = (LAYER == 1) ? a_emb : a_prev; o = p_out;
    } else {
        off = off_a; csr = csr_a; rsd = rs_a; rss = rs_p;
        emb = a_emb; prev = a_prev; src = (LAYER == 1) ? p_emb : p_prev; o = a_out;
    }

    int start = off[n], end = off[n + 1];
    int deg = end - start;

    float acc = 0.0f;
    for (int base = start; base < end; base += 64) {
        int m = end - base;
        if (m > 64) m = 64;
        int id = 0;
        float r = 0.0f;
        if (lane < m) {
            id = csr[base + lane];
            r = rss[id];
        }
        for (int i = 0; i < m; ++i) {
            int s = __shfl(id, i, 64);
            float rr = __shfl(r, i, 64);
            acc += rr * src[s * EMB + lane];
        }
    }

    float d = (float)deg;
    float sw = 1.0f - d / (d + EPS);
    int idx = n * EMB + lane;
    float self;
    if (LAYER == 1) self = sw * emb[idx];
    else            self = emb[idx] + (1.0f + sw) * prev[idx];
    o[idx] = self + rsd[n] * acc;
}

// ---------------- batch gather + predict ----------------

__global__ void gather_kernel(const float* __restrict__ fa, const float* __restrict__ fp,
                              const int* __restrict__ authors, const int* __restrict__ papers,
                              float* __restrict__ out, int batch) {
    int t = blockIdx.x * blockDim.x + threadIdx.x;
    int b = t >> 6;
    int d = t & 63;
    if (b >= batch) return;
    float la = fa[authors[b] * EMB + d];
    float lp = fp[papers[b] * EMB + d];
    out[batch + b * EMB + d] = la;                 // latest_author
    out[batch + batch * EMB + b * EMB + d] = lp;   // latest_paper
    float prod = la * lp;
    #pragma unroll
    for (int off = 32; off > 0; off >>= 1)
        prod += __shfl_down(prod, off, 64);
    if (d == 0)
        out[b] = 1.0f / (1.0f + expf(-prod));      // predict
}

// ---------------- launch ----------------

extern "C" void kernel_launch(void* const* d_in, const int* in_sizes, int n_in,
                              void* d_out, int out_size, void* d_ws, size_t ws_size,
                              hipStream_t stream) {
    const float* author_emb = (const float*)d_in[0];
    const float* paper_emb  = (const float*)d_in[1];
    const int*   authors    = (const int*)d_in[2];
    const int*   papers     = (const int*)d_in[3];
    const int*   edge_a     = (const int*)d_in[4];
    const int*   edge_p     = (const int*)d_in[5];
    float* out = (float*)d_out;

    char* ws = (char*)d_ws;
    size_t woff = 0;
    auto alloc = [&](size_t bytes) {
        void* p = ws + woff;
        woff += (bytes + 255) & ~(size_t)255;
        return p;
    };
    int*   off_a = (int*)alloc((NA + 1) * sizeof(int));
    int*   off_p = (int*)alloc((NP + 1) * sizeof(int));
    int*   cnt_a = (int*)alloc(NA * sizeof(int));        // counts, then cursors
    int*   cnt_p = (int*)alloc(NP * sizeof(int));
    int*   bsa   = (int*)alloc(1024 * sizeof(int));
    int*   bsp   = (int*)alloc(1024 * sizeof(int));
    float* rs_a  = (float*)alloc(NA * sizeof(float));
    float* rs_p  = (float*)alloc(NP * sizeof(float));
    int*   csr_a = (int*)alloc((size_t)NE * sizeof(int));
    int*   csr_p = (int*)alloc((size_t)NE * sizeof(int));
    float* a1    = (float*)alloc((size_t)NA * EMB * sizeof(float)); // a1, then fa (in place)
    float* p1    = (float*)alloc((size_t)NP * EMB * sizeof(float));
    float* fp    = (float*)alloc((size_t)NP * EMB * sizeof(float));
    (void)ws_size;

    const int NBA = (NA + 255) / 256;   // 391 scan blocks (authors)
    const int NBP = (NP + 255) / 256;   // 586 scan blocks (papers)

    // 1. CSR build
    hipMemsetAsync(cnt_a, 0, NA * sizeof(int), stream);
    hipMemsetAsync(cnt_p, 0, NP * sizeof(int), stream);
    count_kernel<<<(NE + 255) / 256, 256, 0, stream>>>(edge_a, edge_p, cnt_a, cnt_p);
    scan_part<<<NBA, 256, 0, stream>>>(cnt_a, off_a, bsa, NA);
    scan_part<<<NBP, 256, 0, stream>>>(cnt_p, off_p, bsp, NP);
    scan_top<<<1, 1024, 0, stream>>>(bsa, NBA);
    scan_top<<<1, 1024, 0, stream>>>(bsp, NBP);
    scan_add<<<NBA, 256, 0, stream>>>(off_a, bsa, NA, NE);
    scan_add<<<NBP, 256, 0, stream>>>(off_p, bsp, NP, NE);
    node_prep<<<(NP + 255) / 256, 256, 0, stream>>>(off_a, off_p, rs_a, rs_p, cnt_a, cnt_p);
    fill_kernel<<<(NE + 255) / 256, 256, 0, stream>>>(edge_a, edge_p, cnt_a, cnt_p, csr_a, csr_p);

    // 2. layer 1 (fused papers+authors): a1/p1 from inputs
    {
        long long waves = (long long)(NP + NA);
        pull_kernel<1, 0><<<(unsigned)((waves * 64 + 255) / 256), 256, 0, stream>>>(
            off_a, off_p, csr_a, csr_p, rs_a, rs_p,
            author_emb, paper_emb, author_emb, paper_emb, a1, p1);
    }

    // 3. layer 2: papers first (reads a1), then authors in-place into a1 (reads p1)
    {
        long long waves = NP;
        pull_kernel<2, 1><<<(unsigned)((waves * 64 + 255) / 256), 256, 0, stream>>>(
            off_a, off_p, csr_a, csr_p, rs_a, rs_p,
            author_emb, paper_emb, a1, p1, a1, fp);
    }
    {
        long long waves = NA;
        pull_kernel<2, 2><<<(unsigned)((waves * 64 + 255) / 256), 256, 0, stream>>>(
            off_a, off_p, csr_a, csr_p, rs_a, rs_p,
            author_emb, paper_emb, a1, p1, a1, fp);
    }

    // 4. batch gather + predict
    {
        long long total = (long long)BATCH * 64;
        gather_kernel<<<(unsigned)((total + 255) / 256), 256, 0, stream>>>(
            a1, fp, authors, papers, out, BATCH);
    }
}

// Round 3
// 959.111 us; speedup vs baseline: 3.1499x; 1.6805x over previous
//
#include <hip/hip_runtime.h>
#include <math.h>

#define NA 100000
#define NP 150000
#define EMB 64
#define NE 3200000
#define BATCH 65536
#define EPS 1e-8f

// bucketed counting-sort parameters
#define SH_A 9                                   // author bucket = 512 nodes
#define SH_P 10                                  // paper bucket = 1024 nodes
#define NB_A ((NA + (1 << SH_A) - 1) >> SH_A)    // 196
#define NB_P ((NP + (1 << SH_P) - 1) >> SH_P)    // 147
#define NBT (NB_A + NB_P)                        // 343
#define PACK_SH 18
#define PACK_MASK ((1u << PACK_SH) - 1)          // src id fits 18 bits (<262144)
#define CHUNK 5120

// ---------------- pass 1: global bucket histogram ----------------

__global__ void hist_kernel(const int* __restrict__ ea, const int* __restrict__ ep,
                            int* __restrict__ gh) {
    __shared__ int h[NBT];
    for (int i = threadIdx.x; i < NBT; i += blockDim.x) h[i] = 0;
    __syncthreads();
    int stride = gridDim.x * blockDim.x;
    for (int e = blockIdx.x * blockDim.x + threadIdx.x; e < NE; e += stride) {
        atomicAdd(&h[ea[e] >> SH_A], 1);
        atomicAdd(&h[NB_A + (ep[e] >> SH_P)], 1);
    }
    __syncthreads();
    for (int i = threadIdx.x; i < NBT; i += blockDim.x)
        if (h[i]) atomicAdd(&gh[i], h[i]);
}

// ---------------- pass 2: scan bucket totals (1 block) ----------------

__global__ void bucket_scan(const int* __restrict__ gh, int* __restrict__ bbase_a,
                            int* __restrict__ bbase_p, int* __restrict__ bcur) {
    __shared__ int s[512];
    int t = threadIdx.x;
    int x = (t < NB_A) ? gh[t] : 0;
    s[t] = x;
    __syncthreads();
    for (int o = 1; o < 512; o <<= 1) {
        int v = (t >= o) ? s[t - o] : 0;
        __syncthreads();
        s[t] += v;
        __syncthreads();
    }
    if (t <= NB_A) bbase_a[t] = (t == 0) ? 0 : s[t - 1];
    if (t < NB_A) bcur[t] = (t == 0) ? 0 : s[t - 1];
    __syncthreads();
    int y = (t < NB_P) ? gh[NB_A + t] : 0;
    s[t] = y;
    __syncthreads();
    for (int o = 1; o < 512; o <<= 1) {
        int v = (t >= o) ? s[t - o] : 0;
        __syncthreads();
        s[t] += v;
        __syncthreads();
    }
    if (t <= NB_P) bbase_p[t] = (t == 0) ? 0 : s[t - 1];
    if (t < NB_P) bcur[NB_A + t] = (t == 0) ? 0 : s[t - 1];
}

// ---------------- pass 3: stage packed pairs, bucket-grouped ----------------

__global__ void stage_kernel(const int* __restrict__ ea, const int* __restrict__ ep,
                             int* __restrict__ bcur,
                             unsigned* __restrict__ stg_a, unsigned* __restrict__ stg_p) {
    __shared__ int h[NBT];     // counts, then block's base within bucket region
    __shared__ int lcur[NBT];
    int t = threadIdx.x;
    for (int i = t; i < NBT; i += blockDim.x) h[i] = 0;
    __syncthreads();
    int e0 = blockIdx.x * CHUNK;
    int e1 = min(e0 + CHUNK, NE);
    for (int e = e0 + t; e < e1; e += blockDim.x) {
        atomicAdd(&h[ea[e] >> SH_A], 1);
        atomicAdd(&h[NB_A + (ep[e] >> SH_P)], 1);
    }
    __syncthreads();
    for (int i = t; i < NBT; i += blockDim.x) {
        int c = h[i];
        h[i] = c ? atomicAdd(&bcur[i], c) : 0;
        lcur[i] = 0;
    }
    __syncthreads();
    for (int e = e0 + t; e < e1; e += blockDim.x) {
        int a = ea[e], p = ep[e];
        int ba = a >> SH_A;
        int bp = NB_A + (p >> SH_P);
        int la = atomicAdd(&lcur[ba], 1);
        stg_a[h[ba] + la] = ((unsigned)(a & ((1 << SH_A) - 1)) << PACK_SH) | (unsigned)p;
        int lp = atomicAdd(&lcur[bp], 1);
        stg_p[h[bp] + lp] = ((unsigned)(p & ((1 << SH_P) - 1)) << PACK_SH) | (unsigned)a;
    }
}

// ---------------- pass 4: per-bucket CSR build (off, rs, csr) ----------------

template <int S, int NNODES>
__global__ void build_kernel(const unsigned* __restrict__ stg,
                             const int* __restrict__ bbase,
                             int* __restrict__ off, float* __restrict__ rs,
                             int* __restrict__ csr) {
    __shared__ int cnt[S];
    __shared__ int cur[S];
    __shared__ int tsum[256];
    constexpr int PER = S / 256;
    int b = blockIdx.x;
    int t = threadIdx.x;
    int node0 = b * S;
    int nloc = min(S, NNODES - node0);
    int p0 = bbase[b], p1 = bbase[b + 1];

    for (int i = t; i < S; i += 256) cnt[i] = 0;
    __syncthreads();
    for (int i = p0 + t; i < p1; i += 256)
        atomicAdd(&cnt[stg[i] >> PACK_SH], 1);
    __syncthreads();

    // exclusive scan of cnt[0..S)
    int base_t = t * PER;
    int vals[PER];
    int sum = 0;
    #pragma unroll
    for (int k = 0; k < PER; ++k) { vals[k] = cnt[base_t + k]; sum += vals[k]; }
    tsum[t] = sum;
    __syncthreads();
    for (int o = 1; o < 256; o <<= 1) {
        int v = (t >= o) ? tsum[t - o] : 0;
        __syncthreads();
        tsum[t] += v;
        __syncthreads();
    }
    int excl = (t == 0) ? 0 : tsum[t - 1];
    #pragma unroll
    for (int k = 0; k < PER; ++k) {
        int li = base_t + k;
        if (li < nloc) {
            off[node0 + li] = p0 + excl;
            rs[node0 + li] = rsqrtf((float)vals[k] + EPS);
        }
        cur[li] = p0 + excl;
        excl += vals[k];
    }
    __syncthreads();
    for (int i = p0 + t; i < p1; i += 256) {
        unsigned v = stg[i];
        int slot = atomicAdd(&cur[v >> PACK_SH], 1);
        csr[slot] = (int)(v & PACK_MASK);
    }
    if (b == gridDim.x - 1 && t == 0) off[NNODES] = p1;
}

// ---------------- pull-based conv ----------------
// out[n] = self + rs_dst[n] * sum_e rs_src[src_e]*src[src_e]
// LAYER 1: self = sw*emb,                src = emb
// LAYER 2: self = emb + (1+sw)*prev,     src = prev
// WHICH: 0 = papers+authors fused, 1 = papers only, 2 = authors only
template <int LAYER, int WHICH>
__global__ void pull_kernel(const int* __restrict__ off_a, const int* __restrict__ off_p,
                            const int* __restrict__ csr_a, const int* __restrict__ csr_p,
                            const float* __restrict__ rs_a, const float* __restrict__ rs_p,
                            const float* __restrict__ a_emb, const float* __restrict__ p_emb,
                            const float* __restrict__ a_prev, const float* __restrict__ p_prev,
                            float* __restrict__ a_out, float* __restrict__ p_out) {
    int wave = (int)(((size_t)blockIdx.x * blockDim.x + threadIdx.x) >> 6);
    int lane = threadIdx.x & 63;

    int n;
    const int *off, *csr;
    const float *rsd, *rss, *emb, *prev, *src;
    float* o;
    bool is_paper;
    if (WHICH == 0) {
        if (wave < NP) { is_paper = true; n = wave; }
        else if (wave < NP + NA) { is_paper = false; n = wave - NP; }
        else return;
    } else if (WHICH == 1) {
        if (wave >= NP) return;
        is_paper = true; n = wave;
    } else {
        if (wave >= NA) return;
        is_paper = false; n = wave;
    }
    if (is_paper) {
        off = off_p; csr = csr_p; rsd = rs_p; rss = rs_a;
        emb = p_emb; prev = p_prev; src = (LAYER == 1) ? a_emb : a_prev; o = p_out;
    } else {
        off = off_a; csr = csr_a; rsd = rs_a; rss = rs_p;
        emb = a_emb; prev = a_prev; src = (LAYER == 1) ? p_emb : p_prev; o = a_out;
    }

    int start = off[n], end = off[n + 1];
    int deg = end - start;

    float acc = 0.0f;
    for (int base = start; base < end; base += 64) {
        int m = end - base;
        if (m > 64) m = 64;
        int id = 0;
        float r = 0.0f;
        if (lane < m) {
            id = csr[base + lane];
            r = rss[id];
        }
        for (int i = 0; i < m; ++i) {
            int s = __shfl(id, i, 64);
            float rr = __shfl(r, i, 64);
            acc += rr * src[s * EMB + lane];
        }
    }

    float d = (float)deg;
    float sw = 1.0f - d / (d + EPS);
    int idx = n * EMB + lane;
    float self;
    if (LAYER == 1) self = sw * emb[idx];
    else            self = emb[idx] + (1.0f + sw) * prev[idx];
    o[idx] = self + rsd[n] * acc;
}

// ---------------- batch gather + predict ----------------

__global__ void gather_kernel(const float* __restrict__ fa, const float* __restrict__ fp,
                              const int* __restrict__ authors, const int* __restrict__ papers,
                              float* __restrict__ out, int batch) {
    int t = blockIdx.x * blockDim.x + threadIdx.x;
    int b = t >> 6;
    int d = t & 63;
    if (b >= batch) return;
    float la = fa[authors[b] * EMB + d];
    float lp = fp[papers[b] * EMB + d];
    out[batch + b * EMB + d] = la;                 // latest_author
    out[batch + batch * EMB + b * EMB + d] = lp;   // latest_paper
    float prod = la * lp;
    #pragma unroll
    for (int off = 32; off > 0; off >>= 1)
        prod += __shfl_down(prod, off, 64);
    if (d == 0)
        out[b] = 1.0f / (1.0f + expf(-prod));      // predict
}

// ---------------- launch ----------------

extern "C" void kernel_launch(void* const* d_in, const int* in_sizes, int n_in,
                              void* d_out, int out_size, void* d_ws, size_t ws_size,
                              hipStream_t stream) {
    const float* author_emb = (const float*)d_in[0];
    const float* paper_emb  = (const float*)d_in[1];
    const int*   authors    = (const int*)d_in[2];
    const int*   papers     = (const int*)d_in[3];
    const int*   edge_a     = (const int*)d_in[4];
    const int*   edge_p     = (const int*)d_in[5];
    float* out = (float*)d_out;

    char* ws = (char*)d_ws;
    size_t woff = 0;
    auto alloc = [&](size_t bytes) {
        void* p = ws + woff;
        woff += (bytes + 255) & ~(size_t)255;
        return p;
    };
    int*   gh      = (int*)alloc(NBT * sizeof(int));
    int*   bbase_a = (int*)alloc((NB_A + 1) * sizeof(int));
    int*   bbase_p = (int*)alloc((NB_P + 1) * sizeof(int));
    int*   bcur    = (int*)alloc(NBT * sizeof(int));
    int*   off_a   = (int*)alloc((NA + 1) * sizeof(int));
    int*   off_p   = (int*)alloc((NP + 1) * sizeof(int));
    float* rs_a    = (float*)alloc(NA * sizeof(float));
    float* rs_p    = (float*)alloc(NP * sizeof(float));
    int*   csr_a   = (int*)alloc((size_t)NE * sizeof(int));
    int*   csr_p   = (int*)alloc((size_t)NE * sizeof(int));
    float* a1      = (float*)alloc((size_t)NA * EMB * sizeof(float)); // aliases stg_a
    float* p1      = (float*)alloc((size_t)NP * EMB * sizeof(float)); // aliases stg_p
    float* fp      = (float*)alloc((size_t)NP * EMB * sizeof(float));
    unsigned* stg_a = (unsigned*)a1;   // NE*4B = 12.8MB <= 25.6MB, dead before a1 written
    unsigned* stg_p = (unsigned*)p1;   // 12.8MB <= 38.4MB
    (void)ws_size;

    // CSR build via bucketed counting sort
    hipMemsetAsync(gh, 0, NBT * sizeof(int), stream);
    hist_kernel<<<512, 256, 0, stream>>>(edge_a, edge_p, gh);
    bucket_scan<<<1, 512, 0, stream>>>(gh, bbase_a, bbase_p, bcur);
    stage_kernel<<<(NE + CHUNK - 1) / CHUNK, 256, 0, stream>>>(edge_a, edge_p, bcur, stg_a, stg_p);
    build_kernel<512, NA><<<NB_A, 256, 0, stream>>>(stg_a, bbase_a, off_a, rs_a, csr_a);
    build_kernel<1024, NP><<<NB_P, 256, 0, stream>>>(stg_p, bbase_p, off_p, rs_p, csr_p);

    // layer 1 (fused papers+authors): a1/p1 from inputs
    {
        long long waves = (long long)(NP + NA);
        pull_kernel<1, 0><<<(unsigned)((waves * 64 + 255) / 256), 256, 0, stream>>>(
            off_a, off_p, csr_a, csr_p, rs_a, rs_p,
            author_emb, paper_emb, author_emb, paper_emb, a1, p1);
    }

    // layer 2: papers first (reads a1), then authors in-place into a1 (reads p1)
    {
        long long waves = NP;
        pull_kernel<2, 1><<<(unsigned)((waves * 64 + 255) / 256), 256, 0, stream>>>(
            off_a, off_p, csr_a, csr_p, rs_a, rs_p,
            author_emb, paper_emb, a1, p1, a1, fp);
    }
    {
        long long waves = NA;
        pull_kernel<2, 2><<<(unsigned)((waves * 64 + 255) / 256), 256, 0, stream>>>(
            off_a, off_p, csr_a, csr_p, rs_a, rs_p,
            author_emb, paper_emb, a1, p1, a1, fp);
    }

    // batch gather + predict
    {
        long long total = (long long)BATCH * 64;
        gather_kernel<<<(unsigned)((total + 255) / 256), 256, 0, stream>>>(
            a1, fp, authors, papers, out, BATCH);
    }
}

// Round 4
// 699.587 us; speedup vs baseline: 4.3184x; 1.3710x over previous
//
#include <hip/hip_runtime.h>
#include <math.h>

#define NA 100000
#define NP 150000
#define EMB 64
#define NE 3200000
#define BATCH 65536
#define EPS 1e-8f

// bucketed counting-sort parameters
#define SH_A 9                                   // author bucket = 512 nodes
#define SH_P 10                                  // paper bucket = 1024 nodes
#define NB_A ((NA + (1 << SH_A) - 1) >> SH_A)    // 196
#define NB_P ((NP + (1 << SH_P) - 1) >> SH_P)    // 147
#define NBT (NB_A + NB_P)                        // 343
#define PACK_SH 18
#define PACK_MASK ((1u << PACK_SH) - 1)
#define CHUNK 5120

// ---------------- pass 1: global bucket histogram ----------------

__global__ void hist_kernel(const int* __restrict__ ea, const int* __restrict__ ep,
                            int* __restrict__ gh) {
    __shared__ int h[NBT];
    for (int i = threadIdx.x; i < NBT; i += blockDim.x) h[i] = 0;
    __syncthreads();
    int stride = gridDim.x * blockDim.x;
    for (int e = blockIdx.x * blockDim.x + threadIdx.x; e < NE; e += stride) {
        atomicAdd(&h[ea[e] >> SH_A], 1);
        atomicAdd(&h[NB_A + (ep[e] >> SH_P)], 1);
    }
    __syncthreads();
    for (int i = threadIdx.x; i < NBT; i += blockDim.x)
        if (h[i]) atomicAdd(&gh[i], h[i]);
}

// ---------------- pass 2: scan bucket totals (1 block) ----------------

__global__ void bucket_scan(const int* __restrict__ gh, int* __restrict__ bbase_a,
                            int* __restrict__ bbase_p, int* __restrict__ bcur) {
    __shared__ int s[512];
    int t = threadIdx.x;
    int x = (t < NB_A) ? gh[t] : 0;
    s[t] = x;
    __syncthreads();
    for (int o = 1; o < 512; o <<= 1) {
        int v = (t >= o) ? s[t - o] : 0;
        __syncthreads();
        s[t] += v;
        __syncthreads();
    }
    if (t <= NB_A) bbase_a[t] = (t == 0) ? 0 : s[t - 1];
    if (t < NB_A) bcur[t] = (t == 0) ? 0 : s[t - 1];
    __syncthreads();
    int y = (t < NB_P) ? gh[NB_A + t] : 0;
    s[t] = y;
    __syncthreads();
    for (int o = 1; o < 512; o <<= 1) {
        int v = (t >= o) ? s[t - o] : 0;
        __syncthreads();
        s[t] += v;
        __syncthreads();
    }
    if (t <= NB_P) bbase_p[t] = (t == 0) ? 0 : s[t - 1];
    if (t < NB_P) bcur[NB_A + t] = (t == 0) ? 0 : s[t - 1];
}

// ---------------- pass 3: stage packed pairs, bucket-grouped ----------------

__global__ void stage_kernel(const int* __restrict__ ea, const int* __restrict__ ep,
                             int* __restrict__ bcur,
                             unsigned* __restrict__ stg_a, unsigned* __restrict__ stg_p) {
    __shared__ int h[NBT];     // counts, then block's base within bucket region
    __shared__ int lcur[NBT];
    int t = threadIdx.x;
    for (int i = t; i < NBT; i += blockDim.x) h[i] = 0;
    __syncthreads();
    int e0 = blockIdx.x * CHUNK;
    int e1 = min(e0 + CHUNK, NE);
    for (int e = e0 + t; e < e1; e += blockDim.x) {
        atomicAdd(&h[ea[e] >> SH_A], 1);
        atomicAdd(&h[NB_A + (ep[e] >> SH_P)], 1);
    }
    __syncthreads();
    for (int i = t; i < NBT; i += blockDim.x) {
        int c = h[i];
        h[i] = c ? atomicAdd(&bcur[i], c) : 0;
        lcur[i] = 0;
    }
    __syncthreads();
    for (int e = e0 + t; e < e1; e += blockDim.x) {
        int a = ea[e], p = ep[e];
        int ba = a >> SH_A;
        int bp = NB_A + (p >> SH_P);
        int la = atomicAdd(&lcur[ba], 1);
        stg_a[h[ba] + la] = ((unsigned)(a & ((1 << SH_A) - 1)) << PACK_SH) | (unsigned)p;
        int lp = atomicAdd(&lcur[bp], 1);
        stg_p[h[bp] + lp] = ((unsigned)(p & ((1 << SH_P) - 1)) << PACK_SH) | (unsigned)a;
    }
}

// ---------------- pass 4: per-bucket CSR build (off, rs, csr) ----------------

template <int S, int NNODES>
__global__ void build_kernel(const unsigned* __restrict__ stg,
                             const int* __restrict__ bbase,
                             int* __restrict__ off, float* __restrict__ rs,
                             int* __restrict__ csr) {
    __shared__ int cnt[S];
    __shared__ int cur[S];
    __shared__ int tsum[256];
    constexpr int PER = S / 256;
    int b = blockIdx.x;
    int t = threadIdx.x;
    int node0 = b * S;
    int nloc = min(S, NNODES - node0);
    int p0 = bbase[b], p1 = bbase[b + 1];

    for (int i = t; i < S; i += 256) cnt[i] = 0;
    __syncthreads();
    for (int i = p0 + t; i < p1; i += 256)
        atomicAdd(&cnt[stg[i] >> PACK_SH], 1);
    __syncthreads();

    // exclusive scan of cnt[0..S)
    int base_t = t * PER;
    int vals[PER];
    int sum = 0;
    #pragma unroll
    for (int k = 0; k < PER; ++k) { vals[k] = cnt[base_t + k]; sum += vals[k]; }
    tsum[t] = sum;
    __syncthreads();
    for (int o = 1; o < 256; o <<= 1) {
        int v = (t >= o) ? tsum[t - o] : 0;
        __syncthreads();
        tsum[t] += v;
        __syncthreads();
    }
    int excl = (t == 0) ? 0 : tsum[t - 1];
    #pragma unroll
    for (int k = 0; k < PER; ++k) {
        int li = base_t + k;
        if (li < nloc) {
            off[node0 + li] = p0 + excl;
            rs[node0 + li] = rsqrtf((float)vals[k] + EPS);
        }
        cur[li] = p0 + excl;
        excl += vals[k];
    }
    __syncthreads();
    for (int i = p0 + t; i < p1; i += 256) {
        unsigned v = stg[i];
        int slot = atomicAdd(&cur[v >> PACK_SH], 1);
        csr[slot] = (int)(v & PACK_MASK);
    }
    if (b == gridDim.x - 1 && t == 0) off[NNODES] = p1;
}

// ---------------- pre-scale rows: s = rs[node] * row ----------------

__global__ void scale_kernel(const float4* __restrict__ a_in, const float4* __restrict__ p_in,
                             const float* __restrict__ rs_a, const float* __restrict__ rs_p,
                             float4* __restrict__ sa, float4* __restrict__ sp) {
    int i = blockIdx.x * blockDim.x + threadIdx.x;
    if (i < NA * 16) {
        float r = rs_a[i >> 4];
        float4 v = a_in[i];
        sa[i] = float4{r * v.x, r * v.y, r * v.z, r * v.w};
    }
    if (i < NP * 16) {
        float r = rs_p[i >> 4];
        float4 v = p_in[i];
        sp[i] = float4{r * v.x, r * v.y, r * v.z, r * v.w};
    }
}

// ---------------- pull-based conv, 4 edges/iter, float4 lanes ----------------
// lane = (slot = lane>>4, q = lane&15); 16 lanes cover one 64-dim row as float4.
// out[n] = self + rs_dst[n] * sum_e scaled_src[e]
// LAYER 1: self = sw*emb            (io written, not read)
// LAYER 2: self = emb + (1+sw)*io   (io updated in place; gathers read scaled copies only)
template <int LAYER>
__global__ void pull4(const int* __restrict__ off_a, const int* __restrict__ off_p,
                      const int* __restrict__ csr_a, const int* __restrict__ csr_p,
                      const float* __restrict__ rs_a, const float* __restrict__ rs_p,
                      const float4* __restrict__ src_from_a,   // scaled author-side rows
                      const float4* __restrict__ src_from_p,   // scaled paper-side rows
                      const float4* __restrict__ a_emb, const float4* __restrict__ p_emb,
                      float4* __restrict__ a_io, float4* __restrict__ p_io) {
    int wave = (int)(((size_t)blockIdx.x * blockDim.x + threadIdx.x) >> 6);
    int lane = threadIdx.x & 63;
    int slot = lane >> 4;
    int q = lane & 15;

    int n;
    bool is_paper;
    if (wave < NP) { is_paper = true; n = wave; }
    else if (wave < NP + NA) { is_paper = false; n = wave - NP; }
    else return;

    const int *off, *csr;
    const float4 *src, *emb;
    float4* io;
    float rsd;
    if (is_paper) { off = off_p; csr = csr_p; src = src_from_a; emb = p_emb; io = p_io; rsd = rs_p[n]; }
    else          { off = off_a; csr = csr_a; src = src_from_p; emb = a_emb; io = a_io; rsd = rs_a[n]; }

    int start = off[n], end = off[n + 1];
    int deg = end - start;

    float ax = 0.0f, ay = 0.0f, az = 0.0f, aw = 0.0f;
    for (int base = start; base < end; base += 64) {
        int m = end - base;
        if (m > 64) m = 64;
        int id = (lane < m) ? csr[base + lane] : 0;
        for (int i = 0; i < m; i += 4) {
            int j = i + slot;
            if (j < m) {
                int s = __shfl(id, j, 64);
                float4 v = src[(size_t)s * 16 + q];
                ax += v.x; ay += v.y; az += v.z; aw += v.w;
            }
        }
    }
    // reduce across the 4 slots (xor groups {q, q+16, q+32, q+48})
    ax += __shfl_xor(ax, 16, 64); ay += __shfl_xor(ay, 16, 64);
    az += __shfl_xor(az, 16, 64); aw += __shfl_xor(aw, 16, 64);
    ax += __shfl_xor(ax, 32, 64); ay += __shfl_xor(ay, 32, 64);
    az += __shfl_xor(az, 32, 64); aw += __shfl_xor(aw, 32, 64);

    if (slot == 0) {
        int idx = n * 16 + q;
        float4 e = emb[idx];
        float d = (float)deg;
        float sw = 1.0f - d / (d + EPS);
        float4 o;
        if (LAYER == 1) {
            o.x = sw * e.x + rsd * ax;
            o.y = sw * e.y + rsd * ay;
            o.z = sw * e.z + rsd * az;
            o.w = sw * e.w + rsd * aw;
        } else {
            float4 pr = io[idx];
            float c = 1.0f + sw;
            o.x = e.x + c * pr.x + rsd * ax;
            o.y = e.y + c * pr.y + rsd * ay;
            o.z = e.z + c * pr.z + rsd * az;
            o.w = e.w + c * pr.w + rsd * aw;
        }
        io[idx] = o;
    }
}

// ---------------- batch gather + predict ----------------

__global__ void gather_kernel(const float* __restrict__ fa, const float* __restrict__ fp,
                              const int* __restrict__ authors, const int* __restrict__ papers,
                              float* __restrict__ out, int batch) {
    int t = blockIdx.x * blockDim.x + threadIdx.x;
    int b = t >> 6;
    int d = t & 63;
    if (b >= batch) return;
    float la = fa[authors[b] * EMB + d];
    float lp = fp[papers[b] * EMB + d];
    out[batch + b * EMB + d] = la;                 // latest_author
    out[batch + batch * EMB + b * EMB + d] = lp;   // latest_paper
    float prod = la * lp;
    #pragma unroll
    for (int off = 32; off > 0; off >>= 1)
        prod += __shfl_down(prod, off, 64);
    if (d == 0)
        out[b] = 1.0f / (1.0f + expf(-prod));      // predict
}

// ---------------- launch ----------------

extern "C" void kernel_launch(void* const* d_in, const int* in_sizes, int n_in,
                              void* d_out, int out_size, void* d_ws, size_t ws_size,
                              hipStream_t stream) {
    const float* author_emb = (const float*)d_in[0];
    const float* paper_emb  = (const float*)d_in[1];
    const int*   authors    = (const int*)d_in[2];
    const int*   papers     = (const int*)d_in[3];
    const int*   edge_a     = (const int*)d_in[4];
    const int*   edge_p     = (const int*)d_in[5];
    float* out = (float*)d_out;

    char* ws = (char*)d_ws;
    size_t woff = 0;
    auto alloc = [&](size_t bytes) {
        void* p = ws + woff;
        woff += (bytes + 255) & ~(size_t)255;
        return p;
    };
    int*   gh      = (int*)alloc(NBT * sizeof(int));
    int*   bbase_a = (int*)alloc((NB_A + 1) * sizeof(int));
    int*   bbase_p = (int*)alloc((NB_P + 1) * sizeof(int));
    int*   bcur    = (int*)alloc(NBT * sizeof(int));
    int*   off_a   = (int*)alloc((NA + 1) * sizeof(int));
    int*   off_p   = (int*)alloc((NP + 1) * sizeof(int));
    float* rs_a    = (float*)alloc(NA * sizeof(float));
    float* rs_p    = (float*)alloc(NP * sizeof(float));
    int*   csr_a   = (int*)alloc((size_t)NE * sizeof(int));
    int*   csr_p   = (int*)alloc((size_t)NE * sizeof(int));
    float* sa      = (float*)alloc((size_t)NA * EMB * sizeof(float)); // scaled author rows (aliases stg_a)
    float* sp      = (float*)alloc((size_t)NP * EMB * sizeof(float)); // scaled paper rows (aliases stg_p)
    float* a1      = (float*)alloc((size_t)NA * EMB * sizeof(float)); // l1 then final author
    float* p1      = (float*)alloc((size_t)NP * EMB * sizeof(float)); // l1 then final paper
    unsigned* stg_a = (unsigned*)sa;   // 12.8MB <= 25.6MB, dead before sa written
    unsigned* stg_p = (unsigned*)sp;   // 12.8MB <= 38.4MB
    (void)ws_size;

    // CSR build via bucketed counting sort
    hipMemsetAsync(gh, 0, NBT * sizeof(int), stream);
    hist_kernel<<<512, 256, 0, stream>>>(edge_a, edge_p, gh);
    bucket_scan<<<1, 512, 0, stream>>>(gh, bbase_a, bbase_p, bcur);
    stage_kernel<<<(NE + CHUNK - 1) / CHUNK, 256, 0, stream>>>(edge_a, edge_p, bcur, stg_a, stg_p);
    build_kernel<512, NA><<<NB_A, 256, 0, stream>>>(stg_a, bbase_a, off_a, rs_a, csr_a);
    build_kernel<1024, NP><<<NB_P, 256, 0, stream>>>(stg_p, bbase_p, off_p, rs_p, csr_p);

    const unsigned SCALE_GRID = (NP * 16 + 255) / 256;
    const unsigned PULL_GRID  = (unsigned)(((long long)(NP + NA) * 64) / 256);

    // layer 1: scale inputs, fused pull into a1/p1
    scale_kernel<<<SCALE_GRID, 256, 0, stream>>>(
        (const float4*)author_emb, (const float4*)paper_emb, rs_a, rs_p,
        (float4*)sa, (float4*)sp);
    pull4<1><<<PULL_GRID, 256, 0, stream>>>(
        off_a, off_p, csr_a, csr_p, rs_a, rs_p,
        (const float4*)sa, (const float4*)sp,
        (const float4*)author_emb, (const float4*)paper_emb,
        (float4*)a1, (float4*)p1);

    // layer 2: scale l1 outputs, fused pull in place (gathers read only sa/sp copies)
    scale_kernel<<<SCALE_GRID, 256, 0, stream>>>(
        (const float4*)a1, (const float4*)p1, rs_a, rs_p,
        (float4*)sa, (float4*)sp);
    pull4<2><<<PULL_GRID, 256, 0, stream>>>(
        off_a, off_p, csr_a, csr_p, rs_a, rs_p,
        (const float4*)sa, (const float4*)sp,
        (const float4*)author_emb, (const float4*)paper_emb,
        (float4*)a1, (float4*)p1);

    // batch gather + predict
    {
        long long total = (long long)BATCH * 64;
        gather_kernel<<<(unsigned)((total + 255) / 256), 256, 0, stream>>>(
            a1, p1, authors, papers, out, BATCH);
    }
}

// Round 5
// 497.827 us; speedup vs baseline: 6.0685x; 1.4053x over previous
//
#include <hip/hip_runtime.h>
#include <hip/hip_bf16.h>
#include <math.h>

#define NA 100000
#define NP 150000
#define EMB 64
#define NE 3200000
#define BATCH 65536
#define EPS 1e-8f

// bucketed counting-sort parameters
#define SH_A 9                                   // author bucket = 512 nodes
#define SH_P 10                                  // paper bucket = 1024 nodes
#define NB_A ((NA + (1 << SH_A) - 1) >> SH_A)    // 196
#define NB_P ((NP + (1 << SH_P) - 1) >> SH_P)    // 147
#define NBT (NB_A + NB_P)                        // 343
#define PACK_SH 18
#define PACK_MASK ((1u << PACK_SH) - 1)
#define CHUNK 5120

__device__ inline unsigned pack_bf16(float a, float b) {
    __hip_bfloat16 ha = __float2bfloat16(a);
    __hip_bfloat16 hb = __float2bfloat16(b);
    unsigned ua = *(unsigned short*)&ha;
    unsigned ub = *(unsigned short*)&hb;
    return ua | (ub << 16);
}

// ---------------- pass 1: global bucket histogram ----------------

__global__ void hist_kernel(const int* __restrict__ ea, const int* __restrict__ ep,
                            int* __restrict__ gh) {
    __shared__ int h[NBT];
    for (int i = threadIdx.x; i < NBT; i += blockDim.x) h[i] = 0;
    __syncthreads();
    int stride = gridDim.x * blockDim.x;
    for (int e = blockIdx.x * blockDim.x + threadIdx.x; e < NE; e += stride) {
        atomicAdd(&h[ea[e] >> SH_A], 1);
        atomicAdd(&h[NB_A + (ep[e] >> SH_P)], 1);
    }
    __syncthreads();
    for (int i = threadIdx.x; i < NBT; i += blockDim.x)
        if (h[i]) atomicAdd(&gh[i], h[i]);
}

// ---------------- pass 2: scan bucket totals (1 block) ----------------

__global__ void bucket_scan(const int* __restrict__ gh, int* __restrict__ bbase_a,
                            int* __restrict__ bbase_p, int* __restrict__ bcur) {
    __shared__ int s[512];
    int t = threadIdx.x;
    int x = (t < NB_A) ? gh[t] : 0;
    s[t] = x;
    __syncthreads();
    for (int o = 1; o < 512; o <<= 1) {
        int v = (t >= o) ? s[t - o] : 0;
        __syncthreads();
        s[t] += v;
        __syncthreads();
    }
    if (t <= NB_A) bbase_a[t] = (t == 0) ? 0 : s[t - 1];
    if (t < NB_A) bcur[t] = (t == 0) ? 0 : s[t - 1];
    __syncthreads();
    int y = (t < NB_P) ? gh[NB_A + t] : 0;
    s[t] = y;
    __syncthreads();
    for (int o = 1; o < 512; o <<= 1) {
        int v = (t >= o) ? s[t - o] : 0;
        __syncthreads();
        s[t] += v;
        __syncthreads();
    }
    if (t <= NB_P) bbase_p[t] = (t == 0) ? 0 : s[t - 1];
    if (t < NB_P) bcur[NB_A + t] = (t == 0) ? 0 : s[t - 1];
}

// ---------------- pass 3: stage packed pairs, bucket-grouped ----------------

__global__ void stage_kernel(const int* __restrict__ ea, const int* __restrict__ ep,
                             int* __restrict__ bcur,
                             unsigned* __restrict__ stg_a, unsigned* __restrict__ stg_p) {
    __shared__ int h[NBT];
    __shared__ int lcur[NBT];
    int t = threadIdx.x;
    for (int i = t; i < NBT; i += blockDim.x) h[i] = 0;
    __syncthreads();
    int e0 = blockIdx.x * CHUNK;
    int e1 = min(e0 + CHUNK, NE);
    for (int e = e0 + t; e < e1; e += blockDim.x) {
        atomicAdd(&h[ea[e] >> SH_A], 1);
        atomicAdd(&h[NB_A + (ep[e] >> SH_P)], 1);
    }
    __syncthreads();
    for (int i = t; i < NBT; i += blockDim.x) {
        int c = h[i];
        h[i] = c ? atomicAdd(&bcur[i], c) : 0;
        lcur[i] = 0;
    }
    __syncthreads();
    for (int e = e0 + t; e < e1; e += blockDim.x) {
        int a = ea[e], p = ep[e];
        int ba = a >> SH_A;
        int bp = NB_A + (p >> SH_P);
        int la = atomicAdd(&lcur[ba], 1);
        stg_a[h[ba] + la] = ((unsigned)(a & ((1 << SH_A) - 1)) << PACK_SH) | (unsigned)p;
        int lp = atomicAdd(&lcur[bp], 1);
        stg_p[h[bp] + lp] = ((unsigned)(p & ((1 << SH_P) - 1)) << PACK_SH) | (unsigned)a;
    }
}

// ---------------- pass 4: per-bucket CSR build (off, rs, csr) ----------------

template <int S, int NNODES>
__global__ void build_kernel(const unsigned* __restrict__ stg,
                             const int* __restrict__ bbase,
                             int* __restrict__ off, float* __restrict__ rs,
                             int* __restrict__ csr) {
    __shared__ int cnt[S];
    __shared__ int cur[S];
    __shared__ int tsum[256];
    constexpr int PER = S / 256;
    int b = blockIdx.x;
    int t = threadIdx.x;
    int node0 = b * S;
    int nloc = min(S, NNODES - node0);
    int p0 = bbase[b], p1 = bbase[b + 1];

    for (int i = t; i < S; i += 256) cnt[i] = 0;
    __syncthreads();
    for (int i = p0 + t; i < p1; i += 256)
        atomicAdd(&cnt[stg[i] >> PACK_SH], 1);
    __syncthreads();

    int base_t = t * PER;
    int vals[PER];
    int sum = 0;
    #pragma unroll
    for (int k = 0; k < PER; ++k) { vals[k] = cnt[base_t + k]; sum += vals[k]; }
    tsum[t] = sum;
    __syncthreads();
    for (int o = 1; o < 256; o <<= 1) {
        int v = (t >= o) ? tsum[t - o] : 0;
        __syncthreads();
        tsum[t] += v;
        __syncthreads();
    }
    int excl = (t == 0) ? 0 : tsum[t - 1];
    #pragma unroll
    for (int k = 0; k < PER; ++k) {
        int li = base_t + k;
        if (li < nloc) {
            off[node0 + li] = p0 + excl;
            rs[node0 + li] = rsqrtf((float)vals[k] + EPS);
        }
        cur[li] = p0 + excl;
        excl += vals[k];
    }
    __syncthreads();
    for (int i = p0 + t; i < p1; i += 256) {
        unsigned v = stg[i];
        int slot = atomicAdd(&cur[v >> PACK_SH], 1);
        csr[slot] = (int)(v & PACK_MASK);
    }
    if (b == gridDim.x - 1 && t == 0) off[NNODES] = p1;
}

// ---------------- scale inputs to bf16: s[n] = rs[n] * row[n] ----------------
// thread i handles 8 dims: node = i>>3, q = i&7

__global__ void scale0_kernel(const float4* __restrict__ a_in, const float4* __restrict__ p_in,
                              const float* __restrict__ rs_a, const float* __restrict__ rs_p,
                              uint4* __restrict__ sa, uint4* __restrict__ sp) {
    int i = blockIdx.x * blockDim.x + threadIdx.x;
    if (i < NA * 8) {
        int n = i >> 3, q = i & 7;
        float r = rs_a[n];
        float4 v0 = a_in[n * 16 + q * 2];
        float4 v1 = a_in[n * 16 + q * 2 + 1];
        uint4 o;
        o.x = pack_bf16(r * v0.x, r * v0.y);
        o.y = pack_bf16(r * v0.z, r * v0.w);
        o.z = pack_bf16(r * v1.x, r * v1.y);
        o.w = pack_bf16(r * v1.z, r * v1.w);
        sa[i] = o;
    }
    if (i < NP * 8) {
        int n = i >> 3, q = i & 7;
        float r = rs_p[n];
        float4 v0 = p_in[n * 16 + q * 2];
        float4 v1 = p_in[n * 16 + q * 2 + 1];
        uint4 o;
        o.x = pack_bf16(r * v0.x, r * v0.y);
        o.y = pack_bf16(r * v0.z, r * v0.w);
        o.z = pack_bf16(r * v1.x, r * v1.y);
        o.w = pack_bf16(r * v1.z, r * v1.w);
        sp[i] = o;
    }
}

// ---------------- pull-based conv, bf16 sources, 8 edges/iter ----------------
// lane = (slot = lane>>3, q = lane&7); 8 lanes cover one 64-dim bf16 row (uint4 each).
// LAYER 1: out = sw*emb + rsd*acc; also writes bf16 rsd*out to s_out
// LAYER 2: out = emb + (1+sw)*io + rsd*acc  (in place; gathers read scaled copies only)
template <int LAYER>
__global__ void pull8(const int* __restrict__ off_a, const int* __restrict__ off_p,
                      const int* __restrict__ csr_a, const int* __restrict__ csr_p,
                      const float* __restrict__ rs_a, const float* __restrict__ rs_p,
                      const uint4* __restrict__ src_from_a,   // scaled author rows (bf16)
                      const uint4* __restrict__ src_from_p,   // scaled paper rows (bf16)
                      const float4* __restrict__ a_emb, const float4* __restrict__ p_emb,
                      float4* __restrict__ a_io, float4* __restrict__ p_io,
                      uint4* __restrict__ sa_out, uint4* __restrict__ sp_out) {
    int wave = (int)(((size_t)blockIdx.x * blockDim.x + threadIdx.x) >> 6);
    int lane = threadIdx.x & 63;
    int slot = lane >> 3;
    int q = lane & 7;

    int n;
    bool is_paper;
    if (wave < NP) { is_paper = true; n = wave; }
    else if (wave < NP + NA) { is_paper = false; n = wave - NP; }
    else return;

    const int *off, *csr;
    const uint4* src;
    const float4* emb;
    float4* io;
    uint4* sout;
    float rsd;
    if (is_paper) {
        off = off_p; csr = csr_p; src = src_from_a; emb = p_emb; io = p_io;
        sout = sp_out; rsd = rs_p[n];
    } else {
        off = off_a; csr = csr_a; src = src_from_p; emb = a_emb; io = a_io;
        sout = sa_out; rsd = rs_a[n];
    }

    int start = off[n], end = off[n + 1];
    int deg = end - start;

    float acc[8] = {0, 0, 0, 0, 0, 0, 0, 0};
    for (int base = start; base < end; base += 64) {
        int m = end - base;
        if (m > 64) m = 64;
        int id = (lane < m) ? csr[base + lane] : 0;
        for (int i = 0; i < m; i += 8) {
            int j = i + slot;
            if (j < m) {
                int s = __shfl(id, j, 64);
                uint4 v = src[(size_t)s * 8 + q];
                acc[0] += __uint_as_float(v.x << 16);
                acc[1] += __uint_as_float(v.x & 0xffff0000u);
                acc[2] += __uint_as_float(v.y << 16);
                acc[3] += __uint_as_float(v.y & 0xffff0000u);
                acc[4] += __uint_as_float(v.z << 16);
                acc[5] += __uint_as_float(v.z & 0xffff0000u);
                acc[6] += __uint_as_float(v.w << 16);
                acc[7] += __uint_as_float(v.w & 0xffff0000u);
            }
        }
    }
    #pragma unroll
    for (int k = 0; k < 8; ++k) {
        acc[k] += __shfl_xor(acc[k], 8, 64);
        acc[k] += __shfl_xor(acc[k], 16, 64);
        acc[k] += __shfl_xor(acc[k], 32, 64);
    }

    if (slot == 0) {
        int f4 = n * 16 + q * 2;
        float4 e0 = emb[f4];
        float4 e1 = emb[f4 + 1];
        float d = (float)deg;
        float sw = 1.0f - d / (d + EPS);
        float o[8];
        if (LAYER == 1) {
            o[0] = sw * e0.x + rsd * acc[0];
            o[1] = sw * e0.y + rsd * acc[1];
            o[2] = sw * e0.z + rsd * acc[2];
            o[3] = sw * e0.w + rsd * acc[3];
            o[4] = sw * e1.x + rsd * acc[4];
            o[5] = sw * e1.y + rsd * acc[5];
            o[6] = sw * e1.z + rsd * acc[6];
            o[7] = sw * e1.w + rsd * acc[7];
            // bf16 scaled copy for layer-2 gathers
            uint4 sv;
            sv.x = pack_bf16(rsd * o[0], rsd * o[1]);
            sv.y = pack_bf16(rsd * o[2], rsd * o[3]);
            sv.z = pack_bf16(rsd * o[4], rsd * o[5]);
            sv.w = pack_bf16(rsd * o[6], rsd * o[7]);
            sout[n * 8 + q] = sv;
        } else {
            float4 pr0 = io[f4];
            float4 pr1 = io[f4 + 1];
            float c = 1.0f + sw;
            o[0] = e0.x + c * pr0.x + rsd * acc[0];
            o[1] = e0.y + c * pr0.y + rsd * acc[1];
            o[2] = e0.z + c * pr0.z + rsd * acc[2];
            o[3] = e0.w + c * pr0.w + rsd * acc[3];
            o[4] = e1.x + c * pr1.x + rsd * acc[4];
            o[5] = e1.y + c * pr1.y + rsd * acc[5];
            o[6] = e1.z + c * pr1.z + rsd * acc[6];
            o[7] = e1.w + c * pr1.w + rsd * acc[7];
        }
        io[f4]     = float4{o[0], o[1], o[2], o[3]};
        io[f4 + 1] = float4{o[4], o[5], o[6], o[7]};
    }
}

// ---------------- batch gather + predict ----------------

__global__ void gather_kernel(const float* __restrict__ fa, const float* __restrict__ fp,
                              const int* __restrict__ authors, const int* __restrict__ papers,
                              float* __restrict__ out, int batch) {
    int t = blockIdx.x * blockDim.x + threadIdx.x;
    int b = t >> 6;
    int d = t & 63;
    if (b >= batch) return;
    float la = fa[authors[b] * EMB + d];
    float lp = fp[papers[b] * EMB + d];
    out[batch + b * EMB + d] = la;                 // latest_author
    out[batch + batch * EMB + b * EMB + d] = lp;   // latest_paper
    float prod = la * lp;
    #pragma unroll
    for (int off = 32; off > 0; off >>= 1)
        prod += __shfl_down(prod, off, 64);
    if (d == 0)
        out[b] = 1.0f / (1.0f + expf(-prod));      // predict
}

// ---------------- launch ----------------

extern "C" void kernel_launch(void* const* d_in, const int* in_sizes, int n_in,
                              void* d_out, int out_size, void* d_ws, size_t ws_size,
                              hipStream_t stream) {
    const float* author_emb = (const float*)d_in[0];
    const float* paper_emb  = (const float*)d_in[1];
    const int*   authors    = (const int*)d_in[2];
    const int*   papers     = (const int*)d_in[3];
    const int*   edge_a     = (const int*)d_in[4];
    const int*   edge_p     = (const int*)d_in[5];
    float* out = (float*)d_out;

    char* ws = (char*)d_ws;
    size_t woff = 0;
    auto alloc = [&](size_t bytes) {
        void* p = ws + woff;
        woff += (bytes + 255) & ~(size_t)255;
        return p;
    };
    int*   gh      = (int*)alloc(NBT * sizeof(int));
    int*   bbase_a = (int*)alloc((NB_A + 1) * sizeof(int));
    int*   bbase_p = (int*)alloc((NB_P + 1) * sizeof(int));
    int*   bcur    = (int*)alloc(NBT * sizeof(int));
    int*   off_a   = (int*)alloc((NA + 1) * sizeof(int));
    int*   off_p   = (int*)alloc((NP + 1) * sizeof(int));
    float* rs_a    = (float*)alloc(NA * sizeof(float));
    float* rs_p    = (float*)alloc(NP * sizeof(float));
    int*   csr_a   = (int*)alloc((size_t)NE * sizeof(int));
    int*   csr_p   = (int*)alloc((size_t)NE * sizeof(int));
    uint4* sa0     = (uint4*)alloc((size_t)NA * EMB * 2);   // bf16 scaled inputs
    uint4* sp0     = (uint4*)alloc((size_t)NP * EMB * 2);
    uint4* sa1     = (uint4*)alloc((size_t)NA * EMB * 2);   // bf16 scaled layer-1 out
    uint4* sp1     = (uint4*)alloc((size_t)NP * EMB * 2);
    float* a1      = (float*)alloc((size_t)NA * EMB * sizeof(float)); // l1 then final author
    float* p1      = (float*)alloc((size_t)NP * EMB * sizeof(float)); // l1 then final paper
    unsigned* stg_a = (unsigned*)a1;   // 12.8MB <= 25.6MB, dead before a1 written
    unsigned* stg_p = (unsigned*)p1;   // 12.8MB <= 38.4MB
    (void)ws_size;

    // CSR build via bucketed counting sort
    hipMemsetAsync(gh, 0, NBT * sizeof(int), stream);
    hist_kernel<<<512, 256, 0, stream>>>(edge_a, edge_p, gh);
    bucket_scan<<<1, 512, 0, stream>>>(gh, bbase_a, bbase_p, bcur);
    stage_kernel<<<(NE + CHUNK - 1) / CHUNK, 256, 0, stream>>>(edge_a, edge_p, bcur, stg_a, stg_p);
    build_kernel<512, NA><<<NB_A, 256, 0, stream>>>(stg_a, bbase_a, off_a, rs_a, csr_a);
    build_kernel<1024, NP><<<NB_P, 256, 0, stream>>>(stg_p, bbase_p, off_p, rs_p, csr_p);

    const unsigned SCALE_GRID = (NP * 8 + 255) / 256;
    const unsigned PULL_GRID  = (unsigned)(((long long)(NP + NA) * 64 + 255) / 256);

    // layer 1: bf16-scale inputs, fused pull (writes a1/p1 fp32 + sa1/sp1 bf16)
    scale0_kernel<<<SCALE_GRID, 256, 0, stream>>>(
        (const float4*)author_emb, (const float4*)paper_emb, rs_a, rs_p, sa0, sp0);
    pull8<1><<<PULL_GRID, 256, 0, stream>>>(
        off_a, off_p, csr_a, csr_p, rs_a, rs_p,
        sa0, sp0,
        (const float4*)author_emb, (const float4*)paper_emb,
        (float4*)a1, (float4*)p1, sa1, sp1);

    // layer 2: fused pull in place (gathers read only sa1/sp1)
    pull8<2><<<PULL_GRID, 256, 0, stream>>>(
        off_a, off_p, csr_a, csr_p, rs_a, rs_p,
        sa1, sp1,
        (const float4*)author_emb, (const float4*)paper_emb,
        (float4*)a1, (float4*)p1, nullptr, nullptr);

    // batch gather + predict
    {
        long long total = (long long)BATCH * 64;
        gather_kernel<<<(unsigned)((total + 255) / 256), 256, 0, stream>>>(
            a1, p1, authors, papers, out, BATCH);
    }
}